// Round 1
// baseline (727.206 us; speedup 1.0000x reference)
//
#include <hip/hip_runtime.h>

// GraphSAGE 3-layer: N=100000, E=3.2M, 128 -> 128 -> 128 -> 64.
// Round 7: XCD-pinned channel-sliced gathers.
//  - All fp16 feature tensors stored SLICE-MAJOR: [8 slabs][N][16ch] (128-ch)
//    or [8 slabs][N][8ch] (64-ch). A slab (3.2 MB / 1.6 MB) fits one XCD's
//    4 MB L2.
//  - gather_mean16/8: slice = blockIdx % 8 -> pinned to XCD slice (dispatch
//    round-robin). Each XCD gathers only its resident slab: L2-miss traffic
//    drops from ~352 MB (random 256B rows, 84% miss) to compulsory slab
//    fills + index stream (~150 MB). Index re-reads (8x12.8 MB) are served
//    by LLC since all 8 XCDs stream the same range near-simultaneously.
//  - Per node: 4 edge-slots x 2 lanes (16ch) / 4 slots x 1 lane (8ch),
//    unroll x4 -> 64 B/lane in flight (ILP preserved vs round 6).
//  - MFMA kernels / cast read+write the sliced layout in-place (fragment
//    loads remain 16B-contiguous); no extra passes.
// CSR build (2-level counting sort) unchanged.

#define NN 100000
#define CHUNK 8192

typedef _Float16 half_t;
typedef __attribute__((ext_vector_type(4))) _Float16 half4v;
typedef __attribute__((ext_vector_type(8))) _Float16 half8v;
typedef __attribute__((ext_vector_type(4))) float float4v;

// ---- Pass A: coarse histogram (LDS-privatized) ----
__global__ __launch_bounds__(256) void coarse_hist_kernel(const int* __restrict__ dst,
                                                          int* __restrict__ ghist, int E) {
    __shared__ int h[1024];
    int tid = threadIdx.x;
    for (int i = tid; i < 1024; i += 256) h[i] = 0;
    __syncthreads();
    int base = blockIdx.x * CHUNK;
    int nE = min(CHUNK, E - base);
    for (int i = tid; i < nE; i += 256) atomicAdd(&h[dst[base + i] >> 7], 1);
    __syncthreads();
    for (int i = tid; i < 1024; i += 256) {
        int v = h[i];
        if (v) atomicAdd(&ghist[i], v);
    }
}

// ---- Pass B: scan 1024 coarse bins ----
__global__ __launch_bounds__(1024) void coarse_scan_kernel(const int* __restrict__ ghist,
                                                           int* __restrict__ cptr,
                                                           int* __restrict__ cfill,
                                                           int* __restrict__ row_ptr,
                                                           int n, int E) {
    __shared__ int s[1024];
    int tid = threadIdx.x;
    s[tid] = ghist[tid];
    __syncthreads();
    for (int off = 1; off < 1024; off <<= 1) {
        int v = (tid >= off) ? s[tid - off] : 0;
        __syncthreads();
        s[tid] += v;
        __syncthreads();
    }
    int excl = (tid == 0) ? 0 : s[tid - 1];
    cptr[tid] = excl;
    cfill[tid] = excl;
    if (tid == 1023) {
        cptr[1024] = s[1023];
        row_ptr[n] = E;
    }
}

// ---- Pass C: partition edges into coarse buckets (packed u32) ----
__global__ __launch_bounds__(256) void partition_kernel(const int* __restrict__ src,
                                                        const int* __restrict__ dst,
                                                        int* __restrict__ cfill,
                                                        unsigned int* __restrict__ coarse,
                                                        int E) {
    __shared__ int h[1024];
    __shared__ int off[1024];
    __shared__ int gbase[1024];
    __shared__ int ssum[256];
    __shared__ unsigned int stage[CHUNK];
    int tid = threadIdx.x;
    for (int i = tid; i < 1024; i += 256) h[i] = 0;
    __syncthreads();
    int base = blockIdx.x * CHUNK;
    int nE = min(CHUNK, E - base);
    for (int i = tid; i < nE; i += 256) atomicAdd(&h[dst[base + i] >> 7], 1);
    __syncthreads();
    int b0 = tid * 4;
    int sum = h[b0] + h[b0 + 1] + h[b0 + 2] + h[b0 + 3];
    ssum[tid] = sum;
    __syncthreads();
    for (int o = 1; o < 256; o <<= 1) {
        int v = (tid >= o) ? ssum[tid - o] : 0;
        __syncthreads();
        ssum[tid] += v;
        __syncthreads();
    }
    int run = (tid == 0) ? 0 : ssum[tid - 1];
#pragma unroll
    for (int j = 0; j < 4; j++) { off[b0 + j] = run; run += h[b0 + j]; }
    __syncthreads();
    for (int i = tid; i < nE; i += 256) {
        int d = dst[base + i];
        int s_ = src[base + i];
        int bin = d >> 7;
        int pos = atomicAdd(&off[bin], 1);
        stage[pos] = ((unsigned)(d & 127) << 17) | (unsigned)s_;
    }
    __syncthreads();
#pragma unroll
    for (int j = 0; j < 4; j++) {
        int b = b0 + j;
        if (h[b]) gbase[b] = atomicAdd(&cfill[b], h[b]);
    }
#pragma unroll
    for (int j = 0; j < 4; j++) {
        int b = b0 + j;
        int c = h[b];
        int lstart = off[b] - c;
        int gs = gbase[b];
        for (int k = 0; k < c; k++) coarse[gs + k] = stage[lstart + k];
    }
}

// ---- Pass D: fine sort within each coarse bucket ----
__global__ __launch_bounds__(256) void fine_sort_kernel(const unsigned int* __restrict__ coarse,
                                                        const int* __restrict__ cptr,
                                                        int* __restrict__ row_ptr,
                                                        int* __restrict__ sorted_src, int n) {
    __shared__ int fh[128];
    __shared__ int foff[128];
    int b = blockIdx.x;
    int beg = cptr[b], end = cptr[b + 1];
    int nb = end - beg;
    int tid = threadIdx.x;
    if (tid < 128) fh[tid] = 0;
    __syncthreads();
    for (int i = tid; i < nb; i += 256) atomicAdd(&fh[coarse[beg + i] >> 17], 1);
    __syncthreads();
    if (tid < 128) foff[tid] = fh[tid];
    __syncthreads();
    for (int o = 1; o < 128; o <<= 1) {
        int v = 0;
        if (tid < 128 && tid >= o) v = foff[tid - o];
        __syncthreads();
        if (tid < 128) foff[tid] += v;
        __syncthreads();
    }
    if (tid < 128) {
        int node = b * 128 + tid;
        if (node < n) row_ptr[node] = beg + foff[tid] - fh[tid];
        foff[tid] -= fh[tid];
    }
    __syncthreads();
    for (int i = tid; i < nb; i += 256) {
        unsigned int p = coarse[beg + i];
        int f = p >> 17;
        int pos = atomicAdd(&foff[f], 1);
        sorted_src[beg + pos] = (int)(p & 0x1FFFF);
    }
}

// ---- fp32 -> fp16 cast, writes slice-major [8][N][16] ----
__global__ void cast_f2h(const float* __restrict__ in, half_t* __restrict__ out, int n4) {
    constexpr size_t SLAB = (size_t)NN * 16;
    int t = blockIdx.x * blockDim.x + threadIdx.x;
    if (t < n4) {
        float4 v = *(const float4*)(in + (size_t)t * 4);
        half4v r = {(half_t)v.x, (half_t)v.y, (half_t)v.z, (half_t)v.w};
        int e = t * 4;
        int node = e >> 7;
        int c = e & 127;
        *(half4v*)(out + (size_t)(c >> 4) * SLAB + (size_t)node * 16 + (c & 15)) = r;
    }
}

// ---- weight prep: fragment-contiguous fp16; all 6 weights in one launch ----
template <int C_IN, int C_OUT>
__device__ inline void prep_one(const float* __restrict__ W, half_t* __restrict__ B, int t) {
    constexpr int NCT = C_OUT / 16;
    if (t >= C_IN * C_OUT) return;
    int jj = t & 7;
    int kq = (t >> 3) & 3;
    int c = (t >> 5) & 15;
    int ct = (t >> 9) % NCT;
    int chunk = t / (512 * NCT);
    int k = chunk * 32 + kq * 8 + jj;
    int j = ct * 16 + c;
    B[t] = (half_t)W[(size_t)j * C_IN + k];
}

__global__ __launch_bounds__(256) void prep_all(
    const float* __restrict__ Wl1, const float* __restrict__ Wr1,
    const float* __restrict__ Wl2, const float* __restrict__ Wr2,
    const float* __restrict__ Wl3, const float* __restrict__ Wr3,
    half_t* Bl1, half_t* Br1, half_t* Bl2, half_t* Br2, half_t* Bl3, half_t* Br3) {
    int b = blockIdx.x;
    int tid = threadIdx.x;
    if (b < 256) {  // 4x 128x128 weights, 64 blocks each
        int sel = b >> 6;
        int t = (b & 63) * 256 + tid;
        const float* W = sel == 0 ? Wl1 : sel == 1 ? Wr1 : sel == 2 ? Wl2 : Wr2;
        half_t* B = sel == 0 ? Bl1 : sel == 1 ? Br1 : sel == 2 ? Bl2 : Br2;
        prep_one<128, 128>(W, B, t);
    } else {  // 2x 64x128 weights, 32 blocks each
        int idx = b - 256;
        int sel = idx >> 5;
        int t = (idx & 31) * 256 + tid;
        prep_one<128, 64>(sel == 0 ? Wl3 : Wr3, sel == 0 ? Bl3 : Br3, t);
    }
}

// ---- gather mean, 16-ch slice of 128-ch slice-major tensor ----
// slice = blockIdx%8 -> pinned to one XCD; that XCD's slab (N*16*2B = 3.2 MB)
// stays resident in its 4 MB L2. Per node: 4 edge-slots x 2 lanes (16B each),
// unroll x4 -> 64B/lane in flight. 8 nodes/wave, 32 nodes/block.
__global__ __launch_bounds__(256) void gather_mean16(
    const half_t* __restrict__ h, const int* __restrict__ row_ptr,
    const int* __restrict__ sorted_src, half_t* __restrict__ mean, int n) {
    constexpr size_t SLAB = (size_t)NN * 16;
    int slice = blockIdx.x & 7;
    int nb = blockIdx.x >> 3;
    int tid = threadIdx.x;
    int lane = tid & 63;
    int node = nb * 32 + (tid >> 6) * 8 + (lane >> 3);
    if (node >= n) return;
    int g = lane & 7;
    int slot = g >> 1;   // edge slot 0..3
    int col = g & 1;     // 16B column slice within 32B row
    const half_t* base = h + (size_t)slice * SLAB + col * 8;
    int beg = row_ptr[node], end = row_ptr[node + 1];
    float a0 = 0.f, a1 = 0.f, a2 = 0.f, a3 = 0.f, a4 = 0.f, a5 = 0.f, a6 = 0.f, a7 = 0.f;
    int j = beg + slot;
    for (; j + 12 < end; j += 16) {
        int s0 = sorted_src[j];
        int s1 = sorted_src[j + 4];
        int s2 = sorted_src[j + 8];
        int s3 = sorted_src[j + 12];
        half8v v0 = *(const half8v*)(base + (size_t)s0 * 16);
        half8v v1 = *(const half8v*)(base + (size_t)s1 * 16);
        half8v v2 = *(const half8v*)(base + (size_t)s2 * 16);
        half8v v3 = *(const half8v*)(base + (size_t)s3 * 16);
        a0 += ((float)v0[0] + (float)v1[0]) + ((float)v2[0] + (float)v3[0]);
        a1 += ((float)v0[1] + (float)v1[1]) + ((float)v2[1] + (float)v3[1]);
        a2 += ((float)v0[2] + (float)v1[2]) + ((float)v2[2] + (float)v3[2]);
        a3 += ((float)v0[3] + (float)v1[3]) + ((float)v2[3] + (float)v3[3]);
        a4 += ((float)v0[4] + (float)v1[4]) + ((float)v2[4] + (float)v3[4]);
        a5 += ((float)v0[5] + (float)v1[5]) + ((float)v2[5] + (float)v3[5]);
        a6 += ((float)v0[6] + (float)v1[6]) + ((float)v2[6] + (float)v3[6]);
        a7 += ((float)v0[7] + (float)v1[7]) + ((float)v2[7] + (float)v3[7]);
    }
    for (; j < end; j += 4) {
        int s0 = sorted_src[j];
        half8v v0 = *(const half8v*)(base + (size_t)s0 * 16);
        a0 += (float)v0[0]; a1 += (float)v0[1]; a2 += (float)v0[2]; a3 += (float)v0[3];
        a4 += (float)v0[4]; a5 += (float)v0[5]; a6 += (float)v0[6]; a7 += (float)v0[7];
    }
    // reduce across the 4 edge slots (lane bits 1,2)
    a0 += __shfl_xor(a0, 2); a1 += __shfl_xor(a1, 2);
    a2 += __shfl_xor(a2, 2); a3 += __shfl_xor(a3, 2);
    a4 += __shfl_xor(a4, 2); a5 += __shfl_xor(a5, 2);
    a6 += __shfl_xor(a6, 2); a7 += __shfl_xor(a7, 2);
    a0 += __shfl_xor(a0, 4); a1 += __shfl_xor(a1, 4);
    a2 += __shfl_xor(a2, 4); a3 += __shfl_xor(a3, 4);
    a4 += __shfl_xor(a4, 4); a5 += __shfl_xor(a5, 4);
    a6 += __shfl_xor(a6, 4); a7 += __shfl_xor(a7, 4);
    if (slot == 0) {
        float inv = (end > beg) ? 1.0f / (float)(end - beg) : 0.0f;
        half8v r = {(half_t)(a0 * inv), (half_t)(a1 * inv), (half_t)(a2 * inv), (half_t)(a3 * inv),
                    (half_t)(a4 * inv), (half_t)(a5 * inv), (half_t)(a6 * inv), (half_t)(a7 * inv)};
        *(half8v*)(mean + (size_t)slice * SLAB + (size_t)node * 16 + col * 8) = r;
    }
}

// ---- gather mean, 8-ch slice of 64-ch slice-major tensor ----
// slab = N*8*2B = 1.6 MB, L2-resident per XCD. Per node: 4 slots x 1 lane,
// 16 B/edge, unroll x4. 16 nodes/wave, 64 nodes/block.
__global__ __launch_bounds__(256) void gather_mean8(
    const half_t* __restrict__ z, const int* __restrict__ row_ptr,
    const int* __restrict__ sorted_src, half_t* __restrict__ mean, int n) {
    constexpr size_t SLAB = (size_t)NN * 8;
    int slice = blockIdx.x & 7;
    int nb = blockIdx.x >> 3;
    int tid = threadIdx.x;
    int lane = tid & 63;
    int node = nb * 64 + (tid >> 6) * 16 + (lane >> 2);
    if (node >= n) return;
    int slot = lane & 3;
    const half_t* base = z + (size_t)slice * SLAB;
    int beg = row_ptr[node], end = row_ptr[node + 1];
    float a0 = 0.f, a1 = 0.f, a2 = 0.f, a3 = 0.f, a4 = 0.f, a5 = 0.f, a6 = 0.f, a7 = 0.f;
    int j = beg + slot;
    for (; j + 12 < end; j += 16) {
        int s0 = sorted_src[j];
        int s1 = sorted_src[j + 4];
        int s2 = sorted_src[j + 8];
        int s3 = sorted_src[j + 12];
        half8v v0 = *(const half8v*)(base + (size_t)s0 * 8);
        half8v v1 = *(const half8v*)(base + (size_t)s1 * 8);
        half8v v2 = *(const half8v*)(base + (size_t)s2 * 8);
        half8v v3 = *(const half8v*)(base + (size_t)s3 * 8);
        a0 += ((float)v0[0] + (float)v1[0]) + ((float)v2[0] + (float)v3[0]);
        a1 += ((float)v0[1] + (float)v1[1]) + ((float)v2[1] + (float)v3[1]);
        a2 += ((float)v0[2] + (float)v1[2]) + ((float)v2[2] + (float)v3[2]);
        a3 += ((float)v0[3] + (float)v1[3]) + ((float)v2[3] + (float)v3[3]);
        a4 += ((float)v0[4] + (float)v1[4]) + ((float)v2[4] + (float)v3[4]);
        a5 += ((float)v0[5] + (float)v1[5]) + ((float)v2[5] + (float)v3[5]);
        a6 += ((float)v0[6] + (float)v1[6]) + ((float)v2[6] + (float)v3[6]);
        a7 += ((float)v0[7] + (float)v1[7]) + ((float)v2[7] + (float)v3[7]);
    }
    for (; j < end; j += 4) {
        int s0 = sorted_src[j];
        half8v v0 = *(const half8v*)(base + (size_t)s0 * 8);
        a0 += (float)v0[0]; a1 += (float)v0[1]; a2 += (float)v0[2]; a3 += (float)v0[3];
        a4 += (float)v0[4]; a5 += (float)v0[5]; a6 += (float)v0[6]; a7 += (float)v0[7];
    }
    // reduce across the 4 edge slots (lane bits 0,1)
    a0 += __shfl_xor(a0, 1); a1 += __shfl_xor(a1, 1);
    a2 += __shfl_xor(a2, 1); a3 += __shfl_xor(a3, 1);
    a4 += __shfl_xor(a4, 1); a5 += __shfl_xor(a5, 1);
    a6 += __shfl_xor(a6, 1); a7 += __shfl_xor(a7, 1);
    a0 += __shfl_xor(a0, 2); a1 += __shfl_xor(a1, 2);
    a2 += __shfl_xor(a2, 2); a3 += __shfl_xor(a3, 2);
    a4 += __shfl_xor(a4, 2); a5 += __shfl_xor(a5, 2);
    a6 += __shfl_xor(a6, 2); a7 += __shfl_xor(a7, 2);
    if (slot == 0) {
        float inv = (end > beg) ? 1.0f / (float)(end - beg) : 0.0f;
        half8v r = {(half_t)(a0 * inv), (half_t)(a1 * inv), (half_t)(a2 * inv), (half_t)(a3 * inv),
                    (half_t)(a4 * inv), (half_t)(a5 * inv), (half_t)(a6 * inv), (half_t)(a7 * inv)};
        *(half8v*)(mean + (size_t)slice * SLAB + (size_t)node * 8) = r;
    }
}

// ---- A-fragment load from slice-major [8][N][16] tensor ----
// channel base k0 = ch*32 + q*8 -> slab 2*ch + (q>>1), offset (q&1)*8.
__device__ inline half8v load_a16(const half_t* __restrict__ A, int rowc, int q, int ch) {
    constexpr size_t SLAB = (size_t)NN * 16;
    return *(const half8v*)(A + (size_t)(2 * ch + (q >> 1)) * SLAB + (size_t)rowc * 16 + (q & 1) * 8);
}

// ---- MFMA two-stage layer (layers 1,2): out16 = relu( mean@Wl^T + bias + root@Wr^T )
//      A inputs and out16 are slice-major [8][N][16]. ----
template <int C_OUT>
__global__ __launch_bounds__(256) void mfma_layer(
    const half_t* __restrict__ rootA, const half_t* __restrict__ meanA,
    const half_t* __restrict__ Bl, const half_t* __restrict__ Br,
    const float* __restrict__ bias, half_t* __restrict__ out16, int n) {
    constexpr int NCT = C_OUT / 16;
    constexpr size_t SLAB = (size_t)NN * 16;
    int tid = threadIdx.x;
    int w = tid >> 6;
    int l = tid & 63;
    int c = l & 15;
    int q = l >> 4;
    int row = blockIdx.x * 64 + w * 16 + c;
    int rowc = min(row, n - 1);

    float4v acc[NCT];
#pragma unroll
    for (int i = 0; i < NCT; i++) acc[i] = (float4v){0.f, 0.f, 0.f, 0.f};

#pragma unroll
    for (int s = 0; s < 2; s++) {
        const half_t* A = (s == 0 ? meanA : rootA);
        const half_t* B = (s == 0 ? Bl : Br) + (size_t)(c * 4 + q) * 8;
#pragma unroll
        for (int ch = 0; ch < 4; ch++) {
            half8v a = load_a16(A, rowc, q, ch);
            half8v b[NCT];
#pragma unroll
            for (int t2 = 0; t2 < NCT; t2++)
                b[t2] = *(const half8v*)(B + (size_t)ch * (NCT * 512) + t2 * 512);
#pragma unroll
            for (int t2 = 0; t2 < NCT; t2++)
                acc[t2] = __builtin_amdgcn_mfma_f32_16x16x32_f16(a, b[t2], acc[t2], 0, 0, 0);
        }
    }

    int orow0 = blockIdx.x * 64 + w * 16 + q * 4;
#pragma unroll
    for (int t2 = 0; t2 < NCT; t2++) {
        float bv = bias[t2 * 16 + c];
#pragma unroll
        for (int r = 0; r < 4; r++) {
            int nrow = orow0 + r;
            if (nrow < n)
                out16[(size_t)t2 * SLAB + (size_t)nrow * 16 + c] = (half_t)fmaxf(acc[t2][r] + bv, 0.f);
        }
    }
}

// ---- MFMA single-stage (layer 3): K=128, A slice-major [8][N][16].
//      out16 (z) and addv (meanz) are slice-major [8][N][8]; out32 row-major. ----
template <int C_OUT, bool HAS_ADD, bool OUT32>
__global__ __launch_bounds__(256) void mfma_single(
    const half_t* __restrict__ A_, const half_t* __restrict__ Bp,
    const half_t* __restrict__ addv, const float* __restrict__ bias,
    float* __restrict__ out32, half_t* __restrict__ out16, int n) {
    constexpr int NCT = C_OUT / 16;
    constexpr size_t SLAB8 = (size_t)NN * 8;
    int tid = threadIdx.x;
    int w = tid >> 6;
    int l = tid & 63;
    int c = l & 15;
    int q = l >> 4;
    int row = blockIdx.x * 64 + w * 16 + c;
    int rowc = min(row, n - 1);

    float4v acc[NCT];
#pragma unroll
    for (int i = 0; i < NCT; i++) acc[i] = (float4v){0.f, 0.f, 0.f, 0.f};

    const half_t* B = Bp + (size_t)(c * 4 + q) * 8;
#pragma unroll
    for (int ch = 0; ch < 4; ch++) {
        half8v a = load_a16(A_, rowc, q, ch);
        half8v b[NCT];
#pragma unroll
        for (int t2 = 0; t2 < NCT; t2++)
            b[t2] = *(const half8v*)(B + (size_t)ch * (NCT * 512) + t2 * 512);
#pragma unroll
        for (int t2 = 0; t2 < NCT; t2++)
            acc[t2] = __builtin_amdgcn_mfma_f32_16x16x32_f16(a, b[t2], acc[t2], 0, 0, 0);
    }

    int orow0 = blockIdx.x * 64 + w * 16 + q * 4;
#pragma unroll
    for (int t2 = 0; t2 < NCT; t2++) {
        int col = t2 * 16 + c;
        float bv = bias ? bias[col] : 0.f;
        size_t soff = (size_t)(col >> 3) * SLAB8 + (size_t)(col & 7);
#pragma unroll
        for (int r = 0; r < 4; r++) {
            int nrow = orow0 + r;
            if (nrow < n) {
                float v = acc[t2][r] + bv;
                if (HAS_ADD) v += (float)addv[soff + (size_t)nrow * 8];
                if (OUT32) out32[(size_t)nrow * C_OUT + col] = v;
                else       out16[soff + (size_t)nrow * 8] = (half_t)v;
            }
        }
    }
}

extern "C" void kernel_launch(void* const* d_in, const int* in_sizes, int n_in,
                              void* d_out, int out_size, void* d_ws, size_t ws_size,
                              hipStream_t stream) {
    const float* x   = (const float*)d_in[0];
    const int*   ei  = (const int*)d_in[1];
    const float* Wl1 = (const float*)d_in[2];
    const float* bl1 = (const float*)d_in[3];
    const float* Wr1 = (const float*)d_in[4];
    const float* Wl2 = (const float*)d_in[5];
    const float* bl2 = (const float*)d_in[6];
    const float* Wr2 = (const float*)d_in[7];
    const float* Wl3 = (const float*)d_in[8];
    const float* bl3 = (const float*)d_in[9];
    const float* Wr3 = (const float*)d_in[10];

    const int N = NN;
    const int E = in_sizes[1] / 2;
    const int* src = ei;
    const int* dst = ei + E;

    char* ws = (char*)d_ws;
    half_t* xh    = (half_t*)ws;                      // N*128 (slice-major [8][N][16])
    half_t* hh    = xh + (size_t)N * 128;             // N*128 (slice-major)
    half_t* meanh = hh + (size_t)N * 128;             // N*128 (slice-major; aliased z|meanz in layer 3)
    half_t* z     = meanh;                            // N*64 (slice-major [8][N][8])
    half_t* meanz = meanh + (size_t)N * 64;           // N*64 (slice-major [8][N][8])
    int* ghist    = (int*)(meanh + (size_t)N * 128);  // 1024
    int* cptr     = ghist + 1024;                     // 1025 (pad 1028)
    int* cfill    = cptr + 1028;                      // 1024
    int* row_ptr  = cfill + 1024;                     // N+1 (pad N+4)
    unsigned int* coarse = (unsigned int*)(row_ptr + N + 4);  // E
    int* sorted_src = (int*)(coarse + E);             // E
    half_t* Bl1 = (half_t*)(sorted_src + E);
    half_t* Br1 = Bl1 + 128 * 128;
    half_t* Bl2 = Br1 + 128 * 128;
    half_t* Br2 = Bl2 + 128 * 128;
    half_t* Bl3 = Br2 + 128 * 128;                    // 64*128
    half_t* Br3 = Bl3 + 64 * 128;

    // casts + weight prep
    cast_f2h<<<(N * 128 / 4 + 255) / 256, 256, 0, stream>>>(x, xh, N * 128 / 4);
    prep_all<<<320, 256, 0, stream>>>(Wl1, Wr1, Wl2, Wr2, Wl3, Wr3,
                                      Bl1, Br1, Bl2, Br2, Bl3, Br3);

    // CSR build: two-level counting sort
    const int sort_blocks = (E + CHUNK - 1) / CHUNK;
    hipMemsetAsync(ghist, 0, 1024 * 4, stream);
    coarse_hist_kernel<<<sort_blocks, 256, 0, stream>>>(dst, ghist, E);
    coarse_scan_kernel<<<1, 1024, 0, stream>>>(ghist, cptr, cfill, row_ptr, N, E);
    partition_kernel<<<sort_blocks, 256, 0, stream>>>(src, dst, cfill, coarse, E);
    fine_sort_kernel<<<(N + 127) / 128, 256, 0, stream>>>(coarse, cptr, row_ptr, sorted_src, N);

    const int g16_blocks = ((N + 31) / 32) * 8;   // 25000: (node-chunk, slice)
    const int g8_blocks  = ((N + 63) / 64) * 8;   // 12504
    const int gemm_blocks = (N + 63) / 64;

    // Layer 1: xh -> hh (relu)
    gather_mean16<<<g16_blocks, 256, 0, stream>>>(xh, row_ptr, sorted_src, meanh, N);
    mfma_layer<128><<<gemm_blocks, 256, 0, stream>>>(xh, meanh, Bl1, Br1, bl1, hh, N);

    // Layer 2: hh -> hh (relu)
    gather_mean16<<<g16_blocks, 256, 0, stream>>>(hh, row_ptr, sorted_src, meanh, N);
    mfma_layer<128><<<gemm_blocks, 256, 0, stream>>>(hh, meanh, Bl2, Br2, bl2, hh, N);

    // Layer 3 (transform-before-aggregate):
    //   z = hh@Wl3^T ; meanz = gather-mean(z) ; out = meanz + bl3 + hh@Wr3^T
    mfma_single<64, false, false><<<gemm_blocks, 256, 0, stream>>>(
        hh, Bl3, nullptr, nullptr, nullptr, z, N);
    gather_mean8<<<g8_blocks, 256, 0, stream>>>(z, row_ptr, sorted_src, meanz, N);
    mfma_single<64, true, true><<<gemm_blocks, 256, 0, stream>>>(
        hh, Br3, meanz, bl3, (float*)d_out, nullptr, N);
}